// Round 1
// 1032.942 us; speedup vs baseline: 1.2883x; 1.2883x over previous
//
#include <hip/hip_runtime.h>

#define NB 32
#define NC 256
#define NH 128
#define NW 128
#define NR 128
#define NF 256
#define HP 126
#define WP 126
#define HWSZ (NH*NW)

typedef __bf16 bf16;
typedef __bf16 bf16x4 __attribute__((ext_vector_type(4)));
typedef __bf16 bf16x8 __attribute__((ext_vector_type(8)));
typedef float  f32x4  __attribute__((ext_vector_type(4)));

// ---------------------------------------------------------------------------
// Kernel 1: channel mix  y2[b,h,w,r] = sum_c f3[c,r] * x[b,c,h,w]   (y2 bf16)
// One block per (b,h): GEMM  D[m=r 128][n=w 128] = f3^T(128x256) * x(256x128).
// Both operands are k(=c)-major in memory, so the transpose is done on the
// GLOBAL side (scalar 4B loads, coalesced across lanes) with vector 16B LDS
// writes; fragments then come out as clean ds_read_b128.
// Output layout [w][r] makes the epilogue an 8B vector store per fragment.
// ---------------------------------------------------------------------------
__global__ __launch_bounds__(256) void k1_chanmix(
    const float* __restrict__ x, const float* __restrict__ f3,
    bf16* __restrict__ y2)
{
    __shared__ __align__(16) bf16 As[128*72];   // A[r][kk], kk = c-c0 (pad 72 -> 144B rows)
    __shared__ __align__(16) bf16 Bs[128*72];   // B^T[w][kk]

    const int t    = threadIdx.x;
    const int b    = blockIdx.x >> 7;
    const int h    = blockIdx.x & 127;
    const int lane = t & 63;
    const int wv   = t >> 6;
    const int lrow = lane & 15;
    const int quad = lane >> 4;
    const int m0   = wv * 32;        // each wave: 32 rows of r, all 128 w

    const int col = t & 127;         // staging column: w for B, r for A
    const int cg0 = t >> 7;          // 0..1

    const float* xcol = x  + (size_t)b*NC*HWSZ + (size_t)h*NW + col;
    const float* fcol = f3 + col;

    f32x4 acc[2][8];
#pragma unroll
    for (int mi=0; mi<2; ++mi)
#pragma unroll
        for (int ni=0; ni<8; ++ni) acc[mi][ni] = (f32x4){0.f,0.f,0.f,0.f};

    for (int c0=0; c0<NC; c0+=64) {
        // stage 64 k-rows of both operands, transposed: scalar coalesced
        // global reads (stride = row pitch), vector 16B LDS writes.
#pragma unroll
        for (int i=0; i<4; ++i) {
            const int cc = (i*2 + cg0)*8;             // chunk-local c base, 0..56
            const float* xp = xcol + (size_t)(c0+cc)*HWSZ;
            bf16x8 bv;
#pragma unroll
            for (int j=0; j<8; ++j) bv[j] = (bf16)xp[(size_t)j*HWSZ];
            *(bf16x8*)(Bs + col*72 + cc) = bv;
            const float* fp = fcol + (size_t)(c0+cc)*NR;
            bf16x8 av;
#pragma unroll
            for (int j=0; j<8; ++j) av[j] = (bf16)fp[(size_t)j*NR];
            *(bf16x8*)(As + col*72 + cc) = av;
        }
        __syncthreads();
#pragma unroll
        for (int ks=0; ks<2; ++ks) {
            const int kc = ks*32 + quad*8;
            bf16x8 af[2], bq[8];
#pragma unroll
            for (int mi=0; mi<2; ++mi)
                af[mi] = *(const bf16x8*)(As + (size_t)(m0 + mi*16 + lrow)*72 + kc);
#pragma unroll
            for (int ni=0; ni<8; ++ni)
                bq[ni] = *(const bf16x8*)(Bs + (size_t)(ni*16 + lrow)*72 + kc);
#pragma unroll
            for (int mi=0; mi<2; ++mi)
#pragma unroll
                for (int ni=0; ni<8; ++ni)
                    acc[mi][ni] = __builtin_amdgcn_mfma_f32_16x16x32_bf16(
                        af[mi], bq[ni], acc[mi][ni], 0, 0, 0);
        }
        __syncthreads();
    }

    // epilogue: C/D layout col(n=w)=lane&15, row(m=r)=quad*4+reg
    // -> 4 consecutive r per fragment = one 8B vector store into y2[b][h][w][r]
    bf16* yrow = y2 + (((size_t)b*NH + h)*NW)*NR;
#pragma unroll
    for (int mi=0; mi<2; ++mi)
#pragma unroll
        for (int ni=0; ni<8; ++ni) {
            const int w = ni*16 + lrow;
            const int r = m0 + mi*16 + quad*4;
            bf16x4 v;
#pragma unroll
            for (int reg=0; reg<4; ++reg) v[reg] = (bf16)acc[mi][ni][reg];
            *(bf16x4*)(yrow + (size_t)w*NR + r) = v;
        }
}

// ---------------------------------------------------------------------------
// Kernel 2: depthwise 3x3 (vectorized over r) + output GEMM.
//   z[w',r] = sum_a f1[a,r] * sum_c f2[c,r] * y2[b,hp+a,w'+c,r]
//   out[b,f,hp,w'] = sum_r f0[f,r] * z[w',r]
// One block (512 thr, 8 waves) per (hp, b). Phase 1: fully coalesced bf16x8
// loads (r innermost), conflict-free 16B LDS writes into Zs[w'][r] -- which is
// already B^T for the GEMM. Phase 2: A-fragments straight from global f0
// (f32->bf16 in-reg, L2-resident), so there is NO staging barrier in the
// k-loop -- a single __syncthreads in the whole kernel.
// ---------------------------------------------------------------------------
__global__ __launch_bounds__(512) void k2_conv_gemm(
    const bf16* __restrict__ y2, const float* __restrict__ f0,
    const float* __restrict__ f1, const float* __restrict__ f2,
    float* __restrict__ out)
{
    __shared__ __align__(16) bf16 Zs[128*136];   // Z^T[w'][r], pad 136 -> 272B rows

    const int t    = threadIdx.x;
    const int hp   = blockIdx.x;
    const int b    = blockIdx.y;
    const int lane = t & 63;
    const int wv   = t >> 6;         // 0..7
    const int lrow = lane & 15;
    const int quad = lane >> 4;
    const int m0   = wv * 32;        // each wave: 32 rows of f, all 128 w'

    // ---- phase 1: build Z^T in LDS, vector over r ----
    const int rc = t & 15;           // r-chunk of 8 (constant per thread)
    {
        float c1[3][8], c2[3][8];
#pragma unroll
        for (int a=0; a<3; ++a) {
            f32x4 l1 = *(const f32x4*)(f1 + a*NR + rc*8);
            f32x4 h1 = *(const f32x4*)(f1 + a*NR + rc*8 + 4);
            f32x4 l2 = *(const f32x4*)(f2 + a*NR + rc*8);
            f32x4 h2 = *(const f32x4*)(f2 + a*NR + rc*8 + 4);
#pragma unroll
            for (int e=0; e<4; ++e) {
                c1[a][e] = l1[e]; c1[a][e+4] = h1[e];
                c2[a][e] = l2[e]; c2[a][e+4] = h2[e];
            }
        }
        const bf16* yb = y2 + (((size_t)b*NH + hp)*NW)*NR + rc*8;
#pragma unroll
        for (int it=0; it<4; ++it) {
            const int wq = it*32 + (t>>4);    // 0..127
            float z[8];
#pragma unroll
            for (int e=0; e<8; ++e) z[e] = 0.f;
            if (wq < WP) {
                const bf16* yp = yb + (size_t)wq*NR;
#pragma unroll
                for (int a=0; a<3; ++a) {
                    float s[8];
#pragma unroll
                    for (int e=0; e<8; ++e) s[e] = 0.f;
#pragma unroll
                    for (int c=0; c<3; ++c) {
                        bf16x8 v = *(const bf16x8*)(yp + ((size_t)a*NW + c)*NR);
#pragma unroll
                        for (int e=0; e<8; ++e) s[e] += c2[c][e]*(float)v[e];
                    }
#pragma unroll
                    for (int e=0; e<8; ++e) z[e] += c1[a][e]*s[e];
                }
            }
            bf16x8 zb;
#pragma unroll
            for (int e=0; e<8; ++e) zb[e] = (bf16)z[e];
            *(bf16x8*)(Zs + wq*136 + rc*8) = zb;   // contiguous 16B, conflict-free
        }
    }
    __syncthreads();

    // ---- phase 2: GEMM, no barriers (Zs is read-only, A comes from global) ----
    f32x4 acc[2][8];
#pragma unroll
    for (int mi=0; mi<2; ++mi)
#pragma unroll
        for (int ni=0; ni<8; ++ni) acc[mi][ni] = (f32x4){0.f,0.f,0.f,0.f};

#pragma unroll
    for (int k0=0; k0<NR; k0+=32) {
        const int kc = k0 + quad*8;
        bf16x8 af[2];
#pragma unroll
        for (int mi=0; mi<2; ++mi) {
            const float* ap = f0 + (size_t)(m0 + mi*16 + lrow)*NR + kc;
            f32x4 lo = *(const f32x4*)ap;
            f32x4 hi = *(const f32x4*)(ap + 4);
            bf16x8 a;
#pragma unroll
            for (int e=0; e<4; ++e) { a[e] = (bf16)lo[e]; a[e+4] = (bf16)hi[e]; }
            af[mi] = a;
        }
        bf16x8 bq[8];
#pragma unroll
        for (int ni=0; ni<8; ++ni)
            bq[ni] = *(const bf16x8*)(Zs + (size_t)(ni*16 + lrow)*136 + kc);
#pragma unroll
        for (int mi=0; mi<2; ++mi)
#pragma unroll
            for (int ni=0; ni<8; ++ni)
                acc[mi][ni] = __builtin_amdgcn_mfma_f32_16x16x32_bf16(
                    af[mi], bq[ni], acc[mi][ni], 0, 0, 0);
    }

    // ---- epilogue: lanes with same quad cover consecutive w' -> 64B-coalesced ----
    float* ob = out + (size_t)b*NF*HP*WP + (size_t)hp*WP;
#pragma unroll
    for (int mi=0; mi<2; ++mi)
#pragma unroll
        for (int ni=0; ni<8; ++ni) {
            const int wp = ni*16 + lrow;
            if (wp < WP) {
#pragma unroll
                for (int reg=0; reg<4; ++reg) {
                    const int f = m0 + mi*16 + quad*4 + reg;
                    ob[(size_t)f*HP*WP + wp] = acc[mi][ni][reg];
                }
            }
        }
}

extern "C" void kernel_launch(void* const* d_in, const int* in_sizes, int n_in,
                              void* d_out, int out_size, void* d_ws, size_t ws_size,
                              hipStream_t stream) {
    const float* x  = (const float*)d_in[0];
    const float* f0 = (const float*)d_in[1];
    const float* f1 = (const float*)d_in[2];
    const float* f2 = (const float*)d_in[3];
    const float* f3 = (const float*)d_in[4];
    float* out = (float*)d_out;
    bf16* y2 = (bf16*)d_ws;   // 32*128*128*128 bf16 = 128 MiB, layout [b][h][w][r]

    hipLaunchKernelGGL(k1_chanmix, dim3(NB*NH), dim3(256), 0, stream, x, f3, y2);
    hipLaunchKernelGGL(k2_conv_gemm, dim3(HP, NB), dim3(512), 0, stream,
                       y2, f0, f1, f2, out);
}